// Round 3
// baseline (317.904 us; speedup 1.0000x reference)
//
#include <hip/hip_runtime.h>
#include <hip/hip_bf16.h>

// K[i,j] = I0(2a*cos(pi*(x_i - y_j))) * exp(-2a),  a = 10.
//
// Key identity: with c = cos(pi*(x-y)) and u = c^2,
//   I0(20c)*e^-20 = e^-20 * sum_{m>=0} (100^m / (m!)^2) u^m
// -- an entire function of u on [0,1] with ALL-POSITIVE coefficients
// (no cancellation; Horner is absolutely stable). Tail after m=23 < 1e-8.
// Verified: sum(A_m) = 0.08978031 = i0e(20) at u=1.
//
// Per element = 1 sub + 1 v_cos_f32 + 1 mul + 23 FMA (no exp/rcp/rsqrt/branch).
// v_cos_f32 takes REVOLUTIONS: cos(pi*d) = v_cos(d/2), so we pre-halve x,y
// and pass hd = x/2 - y/2 directly (|hd| < 0.5 rev, no range reduction).

// clang-native vector type: required by __builtin_nontemporal_store
// (HIP's float4 is a class and is rejected).
typedef float vfloat4 __attribute__((ext_vector_type(4)));

__device__ __forceinline__ float bessel_u(float hd) {
#if __has_builtin(__builtin_amdgcn_cosf)
    float c = __builtin_amdgcn_cosf(hd);           // cos(2*pi*hd) = cos(pi*d)
#else
    float c = __cosf(6.283185307179586f * hd);
#endif
    float u = c * c;
    // A_m = exp(-20) * 100^m / (m!)^2, m = 0..23
    float p =             3.08423e-8f;
    p = fmaf(p, u, 1.63147e-7f);
    p = fmaf(p, u, 7.89629e-7f);
    p = fmaf(p, u, 3.48227e-6f);
    p = fmaf(p, u, 1.39291e-5f);
    p = fmaf(p, u, 5.02842e-5f);
    p = fmaf(p, u, 1.62921e-4f);
    p = fmaf(p, u, 4.70838e-4f);
    p = fmaf(p, u, 1.20534e-3f);
    p = fmaf(p, u, 2.71202e-3f);
    p = fmaf(p, u, 5.31557e-3f);
    p = fmaf(p, u, 8.98331e-3f);
    p = fmaf(p, u, 1.29360e-2f);
    p = fmaf(p, u, 1.56525e-2f);
    p = fmaf(p, u, 1.56525e-2f);
    p = fmaf(p, u, 1.26785e-2f);
    p = fmaf(p, u, 8.11427e-3f);
    p = fmaf(p, u, 3.97599e-3f);
    p = fmaf(p, u, 1.43136e-3f);
    p = fmaf(p, u, 3.57839e-4f);
    p = fmaf(p, u, 5.72543e-5f);
    p = fmaf(p, u, 5.15288e-6f);
    p = fmaf(p, u, 2.06115e-7f);
    p = fmaf(p, u, 2.06115362e-9f);
    return p;
}

// 256 threads/block, 8 elements/thread (two 16B stores).
__global__ __launch_bounds__(256) void bessel_kernel(
    const float* __restrict__ x, const float* __restrict__ y,
    float* __restrict__ out, int nx, int ny)
{
    const int i = blockIdx.y;
    const int j0 = (blockIdx.x * 256 + threadIdx.x) * 8;
    if (i >= nx || j0 >= ny) return;

    const float hx = 0.5f * x[i];                  // block-uniform scalar
    float* orow = out + (size_t)i * (size_t)ny;

    if (j0 + 7 < ny) {
        vfloat4 ya = *reinterpret_cast<const vfloat4*>(y + j0);
        vfloat4 yb = *reinterpret_cast<const vfloat4*>(y + j0 + 4);
        vfloat4 oa, ob;
        oa.x = bessel_u(hx - 0.5f * ya.x);
        oa.y = bessel_u(hx - 0.5f * ya.y);
        oa.z = bessel_u(hx - 0.5f * ya.z);
        oa.w = bessel_u(hx - 0.5f * ya.w);
        ob.x = bessel_u(hx - 0.5f * yb.x);
        ob.y = bessel_u(hx - 0.5f * yb.y);
        ob.z = bessel_u(hx - 0.5f * yb.z);
        ob.w = bessel_u(hx - 0.5f * yb.w);
        __builtin_nontemporal_store(oa, reinterpret_cast<vfloat4*>(orow + j0));
        __builtin_nontemporal_store(ob, reinterpret_cast<vfloat4*>(orow + j0 + 4));
    } else {
        for (int j = j0; j < ny; ++j)
            orow[j] = bessel_u(hx - 0.5f * y[j]);
    }
}

extern "C" void kernel_launch(void* const* d_in, const int* in_sizes, int n_in,
                              void* d_out, int out_size, void* d_ws, size_t ws_size,
                              hipStream_t stream) {
    const float* x = (const float*)d_in[0];
    const float* y = (const float*)d_in[1];
    float* out = (float*)d_out;
    const int nx = in_sizes[0];
    const int ny = in_sizes[1];

    const int jblocks = (ny + 8 * 256 - 1) / (8 * 256);   // 8 elems/thread
    dim3 grid(jblocks, nx);
    bessel_kernel<<<grid, 256, 0, stream>>>(x, y, out, nx, ny);
}